// Round 13
// baseline (138.382 us; speedup 1.0000x reference)
//
#include <hip/hip_runtime.h>
#include <hip/hip_bf16.h>

#define N_NODES 50000
#define E0      800000
#define E_TOT   850000   // +N self loops

typedef short short8 __attribute__((ext_vector_type(8)));
typedef float floatx4 __attribute__((ext_vector_type(4)));

__device__ __forceinline__ float lrelu(float x) { return x > 0.f ? x : 0.2f * x; }

__device__ __forceinline__ unsigned short f2bf(float f) {   // RNE fp32->bf16
    unsigned int u = __float_as_uint(f);
    u += 0x7fffu + ((u >> 16) & 1u);
    return (unsigned short)(u >> 16);
}
__device__ __forceinline__ float lo_bf(unsigned int p) { return __uint_as_float(p << 16); }
__device__ __forceinline__ float hi_bf(unsigned int p) { return __uint_as_float(p & 0xffff0000u); }

__device__ __forceinline__ short8 pack_bf16x8(float4 a, float4 b) {
    short8 r;
    r[0] = (short)f2bf(a.x); r[1] = (short)f2bf(a.y); r[2] = (short)f2bf(a.z); r[3] = (short)f2bf(a.w);
    r[4] = (short)f2bf(b.x); r[5] = (short)f2bf(b.y); r[6] = (short)f2bf(b.z); r[7] = (short)f2bf(b.w);
    return r;
}

__device__ __forceinline__ void fma8(float2* A, float w, uint4 h) {
    A[0].x += w * lo_bf(h.x); A[0].y += w * hi_bf(h.x);
    A[1].x += w * lo_bf(h.y); A[1].y += w * hi_bf(h.y);
    A[2].x += w * lo_bf(h.z); A[2].y += w * hi_bf(h.z);
    A[3].x += w * lo_bf(h.w); A[3].y += w * hi_bf(h.w);
}

// ---------------------------------------------------------------- hist (dst>>8, LDS only) + weight transpose fused
__global__ __launch_bounds__(256) void hist_w(const int* __restrict__ ei, int* __restrict__ ghist,
                                              const float* __restrict__ W1, const float* __restrict__ W2,
                                              unsigned short* __restrict__ Wt1, unsigned short* __restrict__ Wt2) {
    __shared__ int h[256];
    int b = blockIdx.x, t = threadIdx.x;
    h[t] = 0;
    int i = b * 256 + t;
    if (i < 128 * 128) {
        int nn = i >> 7, k = i & 127;
        Wt1[i] = f2bf(W1[k * 128 + nn]);
    } else if (i < 128 * 128 + 48 * 128) {
        int j = i - 128 * 128;
        int nn = j >> 7, k = j & 127;
        Wt2[j] = (nn < 40) ? f2bf(W2[k * 40 + nn]) : (unsigned short)0;
    }
    __syncthreads();
    int base = b * 3328;
    #pragma unroll
    for (int k = 0; k < 13; ++k) {
        int e = base + t + k * 256;
        if (e < E_TOT) {
            int dst = (e < E0) ? ei[E0 + e] : (e - E0);
            atomicAdd(&h[dst >> 8], 1);
        }
    }
    __syncthreads();
    ghist[t * 256 + b] = h[t];      // digit-major layout for the scan
}

// ---------------------------------------------------------------- scans (n=65536, 64 blocks)
__global__ __launch_bounds__(256) void scan_local(const int* __restrict__ src, int* __restrict__ dst,
                                                  int* __restrict__ bsum, int n) {
    __shared__ int wsum[4];
    int t = threadIdx.x, lane = t & 63, wid = t >> 6;
    int idx = blockIdx.x * 1024 + t * 4;
    int4 v = make_int4(0, 0, 0, 0);
    if (idx < n) v = *reinterpret_cast<const int4*>(src + idx);
    int tsum = v.x + v.y + v.z + v.w;
    int sc = tsum;
    #pragma unroll
    for (int s = 1; s < 64; s <<= 1) {
        int up = __shfl_up(sc, s);
        if (lane >= s) sc += up;
    }
    if (lane == 63) wsum[wid] = sc;
    __syncthreads();
    int woff = 0;
    for (int w = 0; w < wid; ++w) woff += wsum[w];
    int b0 = woff + (sc - tsum);
    if (idx < n) {
        int4 o;
        o.x = b0;
        o.y = b0 + v.x;
        o.z = b0 + v.x + v.y;
        o.w = b0 + v.x + v.y + v.z;
        *reinterpret_cast<int4*>(dst + idx) = o;
    }
    if (t == 255) bsum[blockIdx.x] = woff + sc;
}

__global__ __launch_bounds__(256) void scan_addoff(int* __restrict__ arr, const int* __restrict__ bsum,
                                                   int* __restrict__ total, int n, int nb) {
    __shared__ int add_sh;
    int t = threadIdx.x;
    if (t < 64) {
        int v = (t < nb) ? bsum[t] : 0;
        int sc = v;
        #pragma unroll
        for (int s = 1; s < 64; s <<= 1) {
            int up = __shfl_up(sc, s);
            if (t >= s) sc += up;
        }
        if (t == (int)blockIdx.x) add_sh = sc - v;
        if (blockIdx.x == 0 && t == nb - 1) total[0] = sc;
    }
    __syncthreads();
    int idx = blockIdx.x * 1024 + t * 4;
    if (idx < n) {
        int add = add_sh;
        int4 v4 = *reinterpret_cast<int4*>(arr + idx);
        v4.x += add; v4.y += add; v4.z += add; v4.w += add;
        *reinterpret_cast<int4*>(arr + idx) = v4;
    }
}

// ---------------------------------------------------------------- scatter into coarse buckets (LDS cursors only)
__global__ __launch_bounds__(256) void scatter1(const int* __restrict__ ei, const int* __restrict__ gbase,
                                                unsigned int* __restrict__ tmpk) {
    __shared__ int cur[256];
    int b = blockIdx.x, t = threadIdx.x;
    cur[t] = gbase[t * 256 + b];
    __syncthreads();
    int base = b * 3328;
    #pragma unroll
    for (int k = 0; k < 13; ++k) {
        int e = base + t + k * 256;
        if (e < E_TOT) {
            int src, dst;
            if (e < E0) { src = ei[e]; dst = ei[E0 + e]; }
            else        { src = dst = e - E0; }
            int pos = atomicAdd(&cur[dst >> 8], 1);
            tmpk[pos] = ((unsigned)dst << 16) | (unsigned)src;
        }
    }
}

// ---------------------------------------------------------------- in-bucket sort + offs emission + layer-1 edge weights
__global__ __launch_bounds__(256) void sort_w(const unsigned int* __restrict__ tmpk,
                                              const int* __restrict__ gbase,
                                              const float* __restrict__ a_s, const float* __restrict__ a_d,
                                              unsigned int* __restrict__ keys, uint4* __restrict__ ew,
                                              int* __restrict__ offs) {
    __shared__ unsigned int skey[8192];
    __shared__ unsigned int sorted[8192];
    __shared__ int h2[256], binb[256], cur2[256];
    int q = blockIdx.x, t = threadIdx.x;
    int start = gbase[q * 256];
    int end   = gbase[(q + 1) * 256];
    int n = end - start;
    if (n > 8192) n = 8192;     // safety (mean 4336)
    h2[t] = 0;
    __syncthreads();
    for (int i = t; i < n; i += 256) {
        unsigned int k = tmpk[start + i];
        skey[i] = k;
        atomicAdd(&h2[(k >> 16) & 255], 1);
    }
    __syncthreads();
    if (t < 64) {                 // wave-0 exclusive scan over 256 bins
        int carry = 0;
        #pragma unroll
        for (int ch = 0; ch < 4; ++ch) {
            int idx = ch * 64 + t;
            int v = h2[idx];
            int sc = v;
            #pragma unroll
            for (int s = 1; s < 64; s <<= 1) {
                int up = __shfl_up(sc, s);
                if (t >= s) sc += up;
            }
            binb[idx] = sc - v + carry;
            cur2[idx] = sc - v + carry;
            carry += __shfl(sc, 63);
        }
    }
    __syncthreads();
    for (int i = t; i < n; i += 256) {
        unsigned int k = skey[i];
        int pos = atomicAdd(&cur2[(k >> 16) & 255], 1);
        sorted[pos] = k;
    }
    __syncthreads();
    for (int i = t; i < n; i += 256) {
        unsigned int k = sorted[i];
        keys[start + i] = k;
        int src = k & 0xFFFF, dst = k >> 16;
        float2 av = *reinterpret_cast<const float2*>(&a_s[src * 2]);
        float2 dv = *reinterpret_cast<const float2*>(&a_d[dst * 2]);
        uint4 e;
        e.x = k;
        e.y = __float_as_uint(__expf(lrelu(av.x + dv.x)));
        e.z = __float_as_uint(__expf(lrelu(av.y + dv.y)));
        e.w = 0;
        ew[start + i] = e;
    }
    int idx = q * 256 + t;
    if (idx <= N_NODES) offs[idx] = start + binb[t];
}

// ---------------------------------------------------------------- GEMM1 MFMA, LDS-free (X@W1 + att dots)
__global__ __launch_bounds__(256) void gemm1_mfma(const float* __restrict__ X, const unsigned short* __restrict__ Wt,
                                                  const float* __restrict__ asw, const float* __restrict__ adw,
                                                  unsigned short* __restrict__ h1b, float* __restrict__ a_s,
                                                  float* __restrict__ a_d, int nRows) {
    int t = threadIdx.x, lane = t & 63, wave = t >> 6;
    int l15 = lane & 15, g = lane >> 4;
    int r0 = blockIdx.x * 64;
    int row = r0 + wave * 16 + l15;
    bool rv = row < nRows;
    const float* xrow = X + (size_t)(rv ? row : 0) * 128;

    float asv[8], adv[8];
    #pragma unroll
    for (int nt = 0; nt < 8; ++nt) { asv[nt] = asw[nt * 16 + l15]; adv[nt] = adw[nt * 16 + l15]; }

    floatx4 acc[8];
    #pragma unroll
    for (int nt = 0; nt < 8; ++nt) acc[nt] = (floatx4){0.f, 0.f, 0.f, 0.f};

    #pragma unroll
    for (int ks = 0; ks < 4; ++ks) {
        float4 xa = *reinterpret_cast<const float4*>(xrow + ks * 32 + g * 8);
        float4 xb = *reinterpret_cast<const float4*>(xrow + ks * 32 + g * 8 + 4);
        short8 af = pack_bf16x8(xa, xb);
        #pragma unroll
        for (int nt = 0; nt < 8; ++nt) {
            short8 bf = *reinterpret_cast<const short8*>(Wt + (size_t)(nt * 16 + l15) * 128 + ks * 32 + g * 8);
            acc[nt] = __builtin_amdgcn_mfma_f32_16x16x32_bf16(af, bf, acc[nt], 0, 0, 0);
        }
    }

    #pragma unroll
    for (int i = 0; i < 4; ++i) {
        int gr = r0 + wave * 16 + g * 4 + i;
        float s0 = 0.f, d0 = 0.f, s1 = 0.f, d1 = 0.f;
        #pragma unroll
        for (int nt = 0; nt < 4; ++nt) { s0 += acc[nt][i] * asv[nt]; d0 += acc[nt][i] * adv[nt]; }
        #pragma unroll
        for (int nt = 4; nt < 8; ++nt) { s1 += acc[nt][i] * asv[nt]; d1 += acc[nt][i] * adv[nt]; }
        #pragma unroll
        for (int sh = 1; sh < 16; sh <<= 1) {
            s0 += __shfl_xor(s0, sh); d0 += __shfl_xor(d0, sh);
            s1 += __shfl_xor(s1, sh); d1 += __shfl_xor(d1, sh);
        }
        if (gr < nRows) {
            if (l15 == 0) {
                a_s[gr * 2] = s0;     a_d[gr * 2] = d0;
                a_s[gr * 2 + 1] = s1; a_d[gr * 2 + 1] = d1;
            }
            #pragma unroll
            for (int nt = 0; nt < 8; ++nt)
                h1b[(size_t)gr * 128 + nt * 16 + l15] = f2bf(acc[nt][i]);
        }
    }
}

// ---------------------------------------------------------------- GEMM2 MFMA, bf16 input, LDS-free, N=40 (pad 48)
__global__ __launch_bounds__(256) void gemm2_mfma(const unsigned short* __restrict__ X2b,
                                                  const unsigned short* __restrict__ Wt,
                                                  const float* __restrict__ asw, const float* __restrict__ adw,
                                                  unsigned short* __restrict__ h2b, float* __restrict__ a_s,
                                                  float* __restrict__ a_d, int nRows) {
    int t = threadIdx.x, lane = t & 63, wave = t >> 6;
    int l15 = lane & 15, g = lane >> 4;
    int r0 = blockIdx.x * 64;
    int row = r0 + wave * 16 + l15;
    bool rv = row < nRows;
    const unsigned short* xrow = X2b + (size_t)(rv ? row : 0) * 128;

    float asv[3], adv[3];
    #pragma unroll
    for (int nt = 0; nt < 3; ++nt) {
        int col = nt * 16 + l15;
        asv[nt] = (col < 40) ? asw[col] : 0.f;
        adv[nt] = (col < 40) ? adw[col] : 0.f;
    }

    floatx4 acc[3];
    #pragma unroll
    for (int nt = 0; nt < 3; ++nt) acc[nt] = (floatx4){0.f, 0.f, 0.f, 0.f};

    #pragma unroll
    for (int ks = 0; ks < 4; ++ks) {
        short8 af = *reinterpret_cast<const short8*>(xrow + ks * 32 + g * 8);
        #pragma unroll
        for (int nt = 0; nt < 3; ++nt) {
            short8 bf = *reinterpret_cast<const short8*>(Wt + (size_t)(nt * 16 + l15) * 128 + ks * 32 + g * 8);
            acc[nt] = __builtin_amdgcn_mfma_f32_16x16x32_bf16(af, bf, acc[nt], 0, 0, 0);
        }
    }

    #pragma unroll
    for (int i = 0; i < 4; ++i) {
        int gr = r0 + wave * 16 + g * 4 + i;
        float ps = 0.f, pd = 0.f;
        #pragma unroll
        for (int nt = 0; nt < 3; ++nt) { ps += acc[nt][i] * asv[nt]; pd += acc[nt][i] * adv[nt]; }
        #pragma unroll
        for (int sh = 1; sh < 16; sh <<= 1) { ps += __shfl_xor(ps, sh); pd += __shfl_xor(pd, sh); }
        if (gr < nRows) {
            if (l15 == 0) { a_s[gr] = ps; a_d[gr] = pd; }
            #pragma unroll
            for (int nt = 0; nt < 3; ++nt) {
                int col = nt * 16 + l15;
                if (col < 40) h2b[(size_t)gr * 40 + col] = f2bf(acc[nt][i]);
            }
        }
    }
}

// ---------------------------------------------------------------- aggregation layer1 (+bias+ELU) -> bf16 x2
// 1 wave/node; lane=(q=lane>>4, c=lane&15); j-step 16, FOUR independent gathers in flight; packed ew loads
__global__ __launch_bounds__(256) void aggregate1(const unsigned short* __restrict__ Hb,
                                                  const uint4* __restrict__ ew, const int* __restrict__ offs,
                                                  const float* __restrict__ bias,
                                                  unsigned short* __restrict__ X2b, int n) {
    int t = threadIdx.x, lane = t & 63, wid = t >> 6;
    int node = blockIdx.x * 4 + wid;
    if (node >= n) return;
    int c = lane & 15, q = lane >> 4, head = c >> 3;
    int beg = offs[node], deg = offs[node + 1] - beg;
    float den = 0.f;
    float2 acc0[4], acc1[4];
    #pragma unroll
    for (int m = 0; m < 4; ++m) { acc0[m] = make_float2(0.f, 0.f); acc1[m] = make_float2(0.f, 0.f); }

    for (int j = 0; j < deg; j += 16) {
        int sE[4]; float wE[4];
        #pragma unroll
        for (int k2 = 0; k2 < 4; ++k2) {
            int idx = j + 4 * k2 + q;
            sE[k2] = 0; wE[k2] = 0.f;
            if (idx < deg) {
                uint4 e = ew[beg + idx];
                sE[k2] = (int)(e.x & 0xFFFF);
                wE[k2] = __uint_as_float(head ? e.z : e.y);
            }
        }
        uint4 h0 = *reinterpret_cast<const uint4*>(&Hb[(size_t)sE[0] * 128 + c * 8]);
        uint4 h1 = *reinterpret_cast<const uint4*>(&Hb[(size_t)sE[1] * 128 + c * 8]);
        uint4 h2 = *reinterpret_cast<const uint4*>(&Hb[(size_t)sE[2] * 128 + c * 8]);
        uint4 h3 = *reinterpret_cast<const uint4*>(&Hb[(size_t)sE[3] * 128 + c * 8]);
        den += wE[0] + wE[1] + wE[2] + wE[3];
        fma8(acc0, wE[0], h0);
        fma8(acc1, wE[1], h1);
        fma8(acc0, wE[2], h2);
        fma8(acc1, wE[3], h3);
    }
    #pragma unroll
    for (int m = 0; m < 4; ++m) { acc0[m].x += acc1[m].x; acc0[m].y += acc1[m].y; }
    den += __shfl_xor(den, 16); den += __shfl_xor(den, 32);
    #pragma unroll
    for (int m = 0; m < 4; ++m) {
        acc0[m].x += __shfl_xor(acc0[m].x, 16); acc0[m].x += __shfl_xor(acc0[m].x, 32);
        acc0[m].y += __shfl_xor(acc0[m].y, 16); acc0[m].y += __shfl_xor(acc0[m].y, 32);
    }
    if (q == 0) {
        float dinv = 1.f / (den + 1e-16f);
        float4 b0 = *reinterpret_cast<const float4*>(&bias[c * 8]);
        float4 b1 = *reinterpret_cast<const float4*>(&bias[c * 8 + 4]);
        float va[8] = {acc0[0].x, acc0[0].y, acc0[1].x, acc0[1].y, acc0[2].x, acc0[2].y, acc0[3].x, acc0[3].y};
        float bb[8] = {b0.x, b0.y, b0.z, b0.w, b1.x, b1.y, b1.z, b1.w};
        float o[8];
        #pragma unroll
        for (int k = 0; k < 8; ++k) {
            float v = va[k] * dinv + bb[k];
            o[k] = v > 0.f ? v : (__expf(v) - 1.f);   // ELU
        }
        uint4 pk;
        pk.x = (unsigned)f2bf(o[0]) | ((unsigned)f2bf(o[1]) << 16);
        pk.y = (unsigned)f2bf(o[2]) | ((unsigned)f2bf(o[3]) << 16);
        pk.z = (unsigned)f2bf(o[4]) | ((unsigned)f2bf(o[5]) << 16);
        pk.w = (unsigned)f2bf(o[6]) | ((unsigned)f2bf(o[7]) << 16);
        *reinterpret_cast<uint4*>(&X2b[(size_t)node * 128 + c * 8]) = pk;
    }
}

// ---------------------------------------------------------------- aggregation layer2 (+bias) -> out, inline w
__global__ __launch_bounds__(256) void aggregate2(const unsigned short* __restrict__ Hb,
                                                  const float* __restrict__ a_s, const float* __restrict__ a_d,
                                                  const int* __restrict__ offs, const unsigned int* __restrict__ keys,
                                                  const float* __restrict__ bias, float* __restrict__ out, int n) {
    int t = threadIdx.x, lane = t & 63, wid = t >> 6;
    int node = blockIdx.x * 4 + wid;
    if (node >= n) return;
    int g = lane / 5, c = lane - g * 5;
    bool dead = (g >= 12);
    if (dead) { g = 0; c = 0; }
    int beg = offs[node], deg = offs[node + 1] - beg;
    float adv = a_d[node];
    float den = 0.f;
    float2 acc0[4], acc1[4];
    #pragma unroll
    for (int m = 0; m < 4; ++m) { acc0[m] = make_float2(0.f, 0.f); acc1[m] = make_float2(0.f, 0.f); }

    for (int j = 0; j < deg; j += 24) {
        int j0 = j + g, j1 = j + 12 + g;
        int s0 = 0, s1 = 0;
        float w0 = 0.f, w1v = 0.f;
        if (!dead && j0 < deg) {
            s0 = keys[beg + j0] & 0xFFFF;
            w0 = __expf(lrelu(a_s[s0] + adv));
        }
        if (!dead && j1 < deg) {
            s1 = keys[beg + j1] & 0xFFFF;
            w1v = __expf(lrelu(a_s[s1] + adv));
        }
        uint4 h0 = *reinterpret_cast<const uint4*>(&Hb[(size_t)s0 * 40 + c * 8]);
        uint4 h1 = *reinterpret_cast<const uint4*>(&Hb[(size_t)s1 * 40 + c * 8]);
        den += w0 + w1v;
        fma8(acc0, w0, h0);
        fma8(acc1, w1v, h1);
    }
    #pragma unroll
    for (int m = 0; m < 4; ++m) { acc0[m].x += acc1[m].x; acc0[m].y += acc1[m].y; }
    den += __shfl(den, lane + 30);
    den += __shfl(den, lane + 15);
    {
        float d5 = __shfl(den, lane + 5), d10 = __shfl(den, lane + 10);
        den = den + d5 + d10;
    }
    #pragma unroll
    for (int m = 0; m < 4; ++m) {
        float ax = acc0[m].x, ay = acc0[m].y;
        ax += __shfl(ax, lane + 30); ay += __shfl(ay, lane + 30);
        ax += __shfl(ax, lane + 15); ay += __shfl(ay, lane + 15);
        float ax5 = __shfl(ax, lane + 5),  ay5 = __shfl(ay, lane + 5);
        float ax10 = __shfl(ax, lane + 10), ay10 = __shfl(ay, lane + 10);
        acc0[m].x = ax + ax5 + ax10;
        acc0[m].y = ay + ay5 + ay10;
    }
    if (lane < 5) {
        float dinv = 1.f / (den + 1e-16f);
        float4 b0 = *reinterpret_cast<const float4*>(&bias[c * 8]);
        float4 b1 = *reinterpret_cast<const float4*>(&bias[c * 8 + 4]);
        float4 o0, o1;
        o0.x = acc0[0].x * dinv + b0.x; o0.y = acc0[0].y * dinv + b0.y;
        o0.z = acc0[1].x * dinv + b0.z; o0.w = acc0[1].y * dinv + b0.w;
        o1.x = acc0[2].x * dinv + b1.x; o1.y = acc0[2].y * dinv + b1.y;
        o1.z = acc0[3].x * dinv + b1.z; o1.w = acc0[3].y * dinv + b1.w;
        *reinterpret_cast<float4*>(&out[(size_t)node * 40 + c * 8])     = o0;
        *reinterpret_cast<float4*>(&out[(size_t)node * 40 + c * 8 + 4]) = o1;
    }
}

// ---------------------------------------------------------------- launch
extern "C" void kernel_launch(void* const* d_in, const int* in_sizes, int n_in,
                              void* d_out, int out_size, void* d_ws, size_t ws_size,
                              hipStream_t stream) {
    (void)in_sizes; (void)n_in; (void)out_size; (void)ws_size;
    const float* x    = (const float*)d_in[0];
    const int*   ei   = (const int*)d_in[1];
    const float* W1   = (const float*)d_in[2];
    const float* as1w = (const float*)d_in[3];
    const float* ad1w = (const float*)d_in[4];
    const float* b1   = (const float*)d_in[5];
    const float* W2   = (const float*)d_in[6];
    const float* as2w = (const float*)d_in[7];
    const float* ad2w = (const float*)d_in[8];
    const float* b2   = (const float*)d_in[9];
    float* out = (float*)d_out;

    float* ws = (float*)d_ws;
    float* h1slot = ws; ws += (size_t)N_NODES * 128;
    float* x2slot = ws; ws += (size_t)N_NODES * 128;
    float* a_s1 = ws; ws += N_NODES * 2;
    float* a_d1 = ws; ws += N_NODES * 2;
    float* a_s2 = ws; ws += N_NODES;
    float* a_d2 = ws; ws += N_NODES;
    float* h2slot = ws; ws += (size_t)N_NODES * 40;
    int* offs  = (int*)ws;                               // 50432
    int* ghist = offs + 50432;                           // 65536
    int* gbase = ghist + 65536;                          // 65536
    int* bsum  = gbase + 65536;                          // 64
    int* total = bsum + 64;                              // 4
    unsigned int* tmpk = (unsigned int*)(total + 4);     // E_TOT
    unsigned int* keys = tmpk + E_TOT;                   // E_TOT
    uint4* ew = (uint4*)(keys + E_TOT);                  // E_TOT uint4
    unsigned short* Wt1 = (unsigned short*)(ew + E_TOT);
    unsigned short* Wt2 = Wt1 + 128 * 128;

    unsigned short* h1b = (unsigned short*)h1slot;
    unsigned short* x2b = (unsigned short*)x2slot;
    unsigned short* h2b = (unsigned short*)h2slot;

    hist_w<<<256, 256, 0, stream>>>(ei, ghist, W1, W2, Wt1, Wt2);
    scan_local<<<64, 256, 0, stream>>>(ghist, gbase, bsum, 65536);
    scan_addoff<<<64, 256, 0, stream>>>(gbase, bsum, total, 65536, 64);
    scatter1<<<256, 256, 0, stream>>>(ei, gbase, tmpk);
    gemm1_mfma<<<(N_NODES + 63) / 64, 256, 0, stream>>>(x, Wt1, as1w, ad1w, h1b, a_s1, a_d1, N_NODES);
    sort_w<<<196, 256, 0, stream>>>(tmpk, gbase, a_s1, a_d1, keys, ew, offs);
    aggregate1<<<(N_NODES + 3) / 4, 256, 0, stream>>>(h1b, ew, offs, b1, x2b, N_NODES);
    gemm2_mfma<<<(N_NODES + 63) / 64, 256, 0, stream>>>(x2b, Wt2, as2w, ad2w, h2b, a_s2, a_d2, N_NODES);
    aggregate2<<<(N_NODES + 3) / 4, 256, 0, stream>>>(h2b, a_s2, a_d2, offs, keys, b2, out, N_NODES);
}

// Round 14
// 124.132 us; speedup vs baseline: 1.1148x; 1.1148x over previous
//
#include <hip/hip_runtime.h>
#include <hip/hip_bf16.h>

#define N_NODES 50000
#define E0      800000
#define E_TOT   850000   // +N self loops
#define G1_BLOCKS 782    // (N_NODES+63)/64

typedef short short8 __attribute__((ext_vector_type(8)));
typedef float floatx4 __attribute__((ext_vector_type(4)));

__device__ __forceinline__ float lrelu(float x) { return x > 0.f ? x : 0.2f * x; }

__device__ __forceinline__ unsigned short f2bf(float f) {   // RNE fp32->bf16
    unsigned int u = __float_as_uint(f);
    u += 0x7fffu + ((u >> 16) & 1u);
    return (unsigned short)(u >> 16);
}
__device__ __forceinline__ float lo_bf(unsigned int p) { return __uint_as_float(p << 16); }
__device__ __forceinline__ float hi_bf(unsigned int p) { return __uint_as_float(p & 0xffff0000u); }

__device__ __forceinline__ short8 pack_bf16x8(float4 a, float4 b) {
    short8 r;
    r[0] = (short)f2bf(a.x); r[1] = (short)f2bf(a.y); r[2] = (short)f2bf(a.z); r[3] = (short)f2bf(a.w);
    r[4] = (short)f2bf(b.x); r[5] = (short)f2bf(b.y); r[6] = (short)f2bf(b.z); r[7] = (short)f2bf(b.w);
    return r;
}

__device__ __forceinline__ void fma8(float2* A, float w, uint4 h) {
    A[0].x += w * lo_bf(h.x); A[0].y += w * hi_bf(h.x);
    A[1].x += w * lo_bf(h.y); A[1].y += w * hi_bf(h.y);
    A[2].x += w * lo_bf(h.z); A[2].y += w * hi_bf(h.z);
    A[3].x += w * lo_bf(h.w); A[3].y += w * hi_bf(h.w);
}

// ---------------------------------------------------------------- hist (dst>>8, LDS only) + weight transpose fused
__global__ __launch_bounds__(256) void hist_w(const int* __restrict__ ei, int* __restrict__ ghist,
                                              const float* __restrict__ W1, const float* __restrict__ W2,
                                              unsigned short* __restrict__ Wt1, unsigned short* __restrict__ Wt2) {
    __shared__ int h[256];
    int b = blockIdx.x, t = threadIdx.x;
    h[t] = 0;
    int i = b * 256 + t;
    if (i < 128 * 128) {
        int nn = i >> 7, k = i & 127;
        Wt1[i] = f2bf(W1[k * 128 + nn]);
    } else if (i < 128 * 128 + 48 * 128) {
        int j = i - 128 * 128;
        int nn = j >> 7, k = j & 127;
        Wt2[j] = (nn < 40) ? f2bf(W2[k * 40 + nn]) : (unsigned short)0;
    }
    __syncthreads();
    int base = b * 3328;
    #pragma unroll
    for (int k = 0; k < 13; ++k) {
        int e = base + t + k * 256;
        if (e < E_TOT) {
            int dst = (e < E0) ? ei[E0 + e] : (e - E0);
            atomicAdd(&h[dst >> 8], 1);
        }
    }
    __syncthreads();
    ghist[t * 256 + b] = h[t];      // digit-major layout for the scan
}

// ---------------------------------------------------------------- scans (n=65536, 64 blocks)
__global__ __launch_bounds__(256) void scan_local(const int* __restrict__ src, int* __restrict__ dst,
                                                  int* __restrict__ bsum, int n) {
    __shared__ int wsum[4];
    int t = threadIdx.x, lane = t & 63, wid = t >> 6;
    int idx = blockIdx.x * 1024 + t * 4;
    int4 v = make_int4(0, 0, 0, 0);
    if (idx < n) v = *reinterpret_cast<const int4*>(src + idx);
    int tsum = v.x + v.y + v.z + v.w;
    int sc = tsum;
    #pragma unroll
    for (int s = 1; s < 64; s <<= 1) {
        int up = __shfl_up(sc, s);
        if (lane >= s) sc += up;
    }
    if (lane == 63) wsum[wid] = sc;
    __syncthreads();
    int woff = 0;
    for (int w = 0; w < wid; ++w) woff += wsum[w];
    int b0 = woff + (sc - tsum);
    if (idx < n) {
        int4 o;
        o.x = b0;
        o.y = b0 + v.x;
        o.z = b0 + v.x + v.y;
        o.w = b0 + v.x + v.y + v.z;
        *reinterpret_cast<int4*>(dst + idx) = o;
    }
    if (t == 255) bsum[blockIdx.x] = woff + sc;
}

__global__ __launch_bounds__(256) void scan_addoff(int* __restrict__ arr, const int* __restrict__ bsum,
                                                   int* __restrict__ total, int n, int nb) {
    __shared__ int add_sh;
    int t = threadIdx.x;
    if (t < 64) {
        int v = (t < nb) ? bsum[t] : 0;
        int sc = v;
        #pragma unroll
        for (int s = 1; s < 64; s <<= 1) {
            int up = __shfl_up(sc, s);
            if (t >= s) sc += up;
        }
        if (t == (int)blockIdx.x) add_sh = sc - v;
        if (blockIdx.x == 0 && t == nb - 1) total[0] = sc;
    }
    __syncthreads();
    int idx = blockIdx.x * 1024 + t * 4;
    if (idx < n) {
        int add = add_sh;
        int4 v4 = *reinterpret_cast<int4*>(arr + idx);
        v4.x += add; v4.y += add; v4.z += add; v4.w += add;
        *reinterpret_cast<int4*>(arr + idx) = v4;
    }
}

// ---------------------------------------------------------------- gemm1 body (device fn)
__device__ __forceinline__ void gemm1_body(int blk, const float* __restrict__ X, const unsigned short* __restrict__ Wt,
                                           const float* __restrict__ asw, const float* __restrict__ adw,
                                           unsigned short* __restrict__ h1b, float* __restrict__ a_s,
                                           float* __restrict__ a_d, int nRows) {
    int t = threadIdx.x, lane = t & 63, wave = t >> 6;
    int l15 = lane & 15, g = lane >> 4;
    int r0 = blk * 64;
    int row = r0 + wave * 16 + l15;
    bool rv = row < nRows;
    const float* xrow = X + (size_t)(rv ? row : 0) * 128;

    float asv[8], adv[8];
    #pragma unroll
    for (int nt = 0; nt < 8; ++nt) { asv[nt] = asw[nt * 16 + l15]; adv[nt] = adw[nt * 16 + l15]; }

    floatx4 acc[8];
    #pragma unroll
    for (int nt = 0; nt < 8; ++nt) acc[nt] = (floatx4){0.f, 0.f, 0.f, 0.f};

    #pragma unroll
    for (int ks = 0; ks < 4; ++ks) {
        float4 xa = *reinterpret_cast<const float4*>(xrow + ks * 32 + g * 8);
        float4 xb = *reinterpret_cast<const float4*>(xrow + ks * 32 + g * 8 + 4);
        short8 af = pack_bf16x8(xa, xb);
        #pragma unroll
        for (int nt = 0; nt < 8; ++nt) {
            short8 bf = *reinterpret_cast<const short8*>(Wt + (size_t)(nt * 16 + l15) * 128 + ks * 32 + g * 8);
            acc[nt] = __builtin_amdgcn_mfma_f32_16x16x32_bf16(af, bf, acc[nt], 0, 0, 0);
        }
    }

    #pragma unroll
    for (int i = 0; i < 4; ++i) {
        int gr = r0 + wave * 16 + g * 4 + i;
        float s0 = 0.f, d0 = 0.f, s1 = 0.f, d1 = 0.f;
        #pragma unroll
        for (int nt = 0; nt < 4; ++nt) { s0 += acc[nt][i] * asv[nt]; d0 += acc[nt][i] * adv[nt]; }
        #pragma unroll
        for (int nt = 4; nt < 8; ++nt) { s1 += acc[nt][i] * asv[nt]; d1 += acc[nt][i] * adv[nt]; }
        #pragma unroll
        for (int sh = 1; sh < 16; sh <<= 1) {
            s0 += __shfl_xor(s0, sh); d0 += __shfl_xor(d0, sh);
            s1 += __shfl_xor(s1, sh); d1 += __shfl_xor(d1, sh);
        }
        if (gr < nRows) {
            if (l15 == 0) {
                a_s[gr * 2] = s0;     a_d[gr * 2] = d0;
                a_s[gr * 2 + 1] = s1; a_d[gr * 2 + 1] = d1;
            }
            #pragma unroll
            for (int nt = 0; nt < 8; ++nt)
                h1b[(size_t)gr * 128 + nt * 16 + l15] = f2bf(acc[nt][i]);
        }
    }
}

// ---------------------------------------------------------------- fused: gemm1 (blocks <G1) || scatter1 (rest)
__global__ __launch_bounds__(256) void gemm1_scatter(const float* __restrict__ X, const unsigned short* __restrict__ Wt,
                                                     const float* __restrict__ asw, const float* __restrict__ adw,
                                                     unsigned short* __restrict__ h1b, float* __restrict__ a_s,
                                                     float* __restrict__ a_d,
                                                     const int* __restrict__ ei, const int* __restrict__ gbase,
                                                     unsigned int* __restrict__ tmpk) {
    __shared__ int cur[256];
    if (blockIdx.x < G1_BLOCKS) {
        gemm1_body(blockIdx.x, X, Wt, asw, adw, h1b, a_s, a_d, N_NODES);
    } else {
        int b = blockIdx.x - G1_BLOCKS, t = threadIdx.x;
        cur[t] = gbase[t * 256 + b];
        __syncthreads();
        int base = b * 3328;
        #pragma unroll
        for (int k = 0; k < 13; ++k) {
            int e = base + t + k * 256;
            if (e < E_TOT) {
                int src, dst;
                if (e < E0) { src = ei[e]; dst = ei[E0 + e]; }
                else        { src = dst = e - E0; }
                int pos = atomicAdd(&cur[dst >> 8], 1);
                tmpk[pos] = ((unsigned)dst << 16) | (unsigned)src;
            }
        }
    }
}

// ---------------------------------------------------------------- in-bucket sort + offs emission + layer-1 edge weights
__global__ __launch_bounds__(256) void sort_w(const unsigned int* __restrict__ tmpk,
                                              const int* __restrict__ gbase,
                                              const float* __restrict__ a_s, const float* __restrict__ a_d,
                                              unsigned int* __restrict__ keys, uint4* __restrict__ ew,
                                              int* __restrict__ offs) {
    __shared__ unsigned int skey[8192];
    __shared__ unsigned int sorted[8192];
    __shared__ int h2[256], binb[256], cur2[256];
    int q = blockIdx.x, t = threadIdx.x;
    int start = gbase[q * 256];
    int end   = gbase[(q + 1) * 256];
    int n = end - start;
    if (n > 8192) n = 8192;     // safety (mean 4336)
    h2[t] = 0;
    __syncthreads();
    for (int i = t; i < n; i += 256) {
        unsigned int k = tmpk[start + i];
        skey[i] = k;
        atomicAdd(&h2[(k >> 16) & 255], 1);
    }
    __syncthreads();
    if (t < 64) {                 // wave-0 exclusive scan over 256 bins
        int carry = 0;
        #pragma unroll
        for (int ch = 0; ch < 4; ++ch) {
            int idx = ch * 64 + t;
            int v = h2[idx];
            int sc = v;
            #pragma unroll
            for (int s = 1; s < 64; s <<= 1) {
                int up = __shfl_up(sc, s);
                if (t >= s) sc += up;
            }
            binb[idx] = sc - v + carry;
            cur2[idx] = sc - v + carry;
            carry += __shfl(sc, 63);
        }
    }
    __syncthreads();
    for (int i = t; i < n; i += 256) {
        unsigned int k = skey[i];
        int pos = atomicAdd(&cur2[(k >> 16) & 255], 1);
        sorted[pos] = k;
    }
    __syncthreads();
    for (int i = t; i < n; i += 256) {
        unsigned int k = sorted[i];
        keys[start + i] = k;
        int src = k & 0xFFFF, dst = k >> 16;
        float2 av = *reinterpret_cast<const float2*>(&a_s[src * 2]);
        float2 dv = *reinterpret_cast<const float2*>(&a_d[dst * 2]);
        uint4 e;
        e.x = k;
        e.y = __float_as_uint(__expf(lrelu(av.x + dv.x)));
        e.z = __float_as_uint(__expf(lrelu(av.y + dv.y)));
        e.w = 0;
        ew[start + i] = e;
    }
    int idx = q * 256 + t;
    if (idx <= N_NODES) offs[idx] = start + binb[t];
}

// ---------------------------------------------------------------- GEMM2 MFMA, bf16 input, LDS-free, N=40 (pad 48)
__global__ __launch_bounds__(256) void gemm2_mfma(const unsigned short* __restrict__ X2b,
                                                  const unsigned short* __restrict__ Wt,
                                                  const float* __restrict__ asw, const float* __restrict__ adw,
                                                  unsigned short* __restrict__ h2b, float* __restrict__ a_s,
                                                  float* __restrict__ a_d, int nRows) {
    int t = threadIdx.x, lane = t & 63, wave = t >> 6;
    int l15 = lane & 15, g = lane >> 4;
    int r0 = blockIdx.x * 64;
    int row = r0 + wave * 16 + l15;
    bool rv = row < nRows;
    const unsigned short* xrow = X2b + (size_t)(rv ? row : 0) * 128;

    float asv[3], adv[3];
    #pragma unroll
    for (int nt = 0; nt < 3; ++nt) {
        int col = nt * 16 + l15;
        asv[nt] = (col < 40) ? asw[col] : 0.f;
        adv[nt] = (col < 40) ? adw[col] : 0.f;
    }

    floatx4 acc[3];
    #pragma unroll
    for (int nt = 0; nt < 3; ++nt) acc[nt] = (floatx4){0.f, 0.f, 0.f, 0.f};

    #pragma unroll
    for (int ks = 0; ks < 4; ++ks) {
        short8 af = *reinterpret_cast<const short8*>(xrow + ks * 32 + g * 8);
        #pragma unroll
        for (int nt = 0; nt < 3; ++nt) {
            short8 bf = *reinterpret_cast<const short8*>(Wt + (size_t)(nt * 16 + l15) * 128 + ks * 32 + g * 8);
            acc[nt] = __builtin_amdgcn_mfma_f32_16x16x32_bf16(af, bf, acc[nt], 0, 0, 0);
        }
    }

    #pragma unroll
    for (int i = 0; i < 4; ++i) {
        int gr = r0 + wave * 16 + g * 4 + i;
        float ps = 0.f, pd = 0.f;
        #pragma unroll
        for (int nt = 0; nt < 3; ++nt) { ps += acc[nt][i] * asv[nt]; pd += acc[nt][i] * adv[nt]; }
        #pragma unroll
        for (int sh = 1; sh < 16; sh <<= 1) { ps += __shfl_xor(ps, sh); pd += __shfl_xor(pd, sh); }
        if (gr < nRows) {
            if (l15 == 0) { a_s[gr] = ps; a_d[gr] = pd; }
            #pragma unroll
            for (int nt = 0; nt < 3; ++nt) {
                int col = nt * 16 + l15;
                if (col < 40) h2b[(size_t)gr * 40 + col] = f2bf(acc[nt][i]);
            }
        }
    }
}

// ---------------------------------------------------------------- aggregation layer1 (+bias+ELU) -> bf16 x2
// 1 wave/node; stage 64 ew entries (one per lane), shfl-broadcast per slot; j-step 8, 2 gathers in flight
__global__ __launch_bounds__(256) void aggregate1(const unsigned short* __restrict__ Hb,
                                                  const uint4* __restrict__ ew, const int* __restrict__ offs,
                                                  const float* __restrict__ bias,
                                                  unsigned short* __restrict__ X2b, int n) {
    int t = threadIdx.x, lane = t & 63, wid = t >> 6;
    int node = blockIdx.x * 4 + wid;
    if (node >= n) return;
    int c = lane & 15, q = lane >> 4, head = c >> 3;
    int beg = offs[node], deg = offs[node + 1] - beg;
    float den0 = 0.f, den1 = 0.f;
    float2 acc0[4], acc1[4];
    #pragma unroll
    for (int m = 0; m < 4; ++m) { acc0[m] = make_float2(0.f, 0.f); acc1[m] = make_float2(0.f, 0.f); }

    for (int base = 0; base < deg; base += 64) {
        int nslots = min(64, deg - base);
        int s_l = 0; float w0_l = 0.f, w1_l = 0.f;
        if (lane < nslots) {
            uint4 e = ew[beg + base + lane];
            s_l = (int)(e.x & 0xFFFFu);
            w0_l = __uint_as_float(e.y);
            w1_l = __uint_as_float(e.z);
        }
        den0 += w0_l; den1 += w1_l;
        for (int j = 0; j < nslots; j += 8) {
            int j0 = j + q, j1 = j + 4 + q;          // <= 63, staged zeros past deg
            int   sa  = __shfl(s_l, j0);
            float wa0 = __shfl(w0_l, j0), wa1 = __shfl(w1_l, j0);
            int   sb  = __shfl(s_l, j1);
            float wb0 = __shfl(w0_l, j1), wb1 = __shfl(w1_l, j1);
            float wa = head ? wa1 : wa0;
            float wb = head ? wb1 : wb0;
            uint4 ha = *reinterpret_cast<const uint4*>(&Hb[(size_t)sa * 128 + c * 8]);
            uint4 hb = *reinterpret_cast<const uint4*>(&Hb[(size_t)sb * 128 + c * 8]);
            fma8(acc0, wa, ha);
            fma8(acc1, wb, hb);
        }
    }
    #pragma unroll
    for (int m = 0; m < 4; ++m) { acc0[m].x += acc1[m].x; acc0[m].y += acc1[m].y; }
    #pragma unroll
    for (int sh = 32; sh > 0; sh >>= 1) { den0 += __shfl_xor(den0, sh); den1 += __shfl_xor(den1, sh); }
    #pragma unroll
    for (int m = 0; m < 4; ++m) {
        acc0[m].x += __shfl_xor(acc0[m].x, 16); acc0[m].x += __shfl_xor(acc0[m].x, 32);
        acc0[m].y += __shfl_xor(acc0[m].y, 16); acc0[m].y += __shfl_xor(acc0[m].y, 32);
    }
    if (q == 0) {
        float den = (head ? den1 : den0) + 1e-16f;
        float dinv = 1.f / den;
        float4 b0 = *reinterpret_cast<const float4*>(&bias[c * 8]);
        float4 b1 = *reinterpret_cast<const float4*>(&bias[c * 8 + 4]);
        float va[8] = {acc0[0].x, acc0[0].y, acc0[1].x, acc0[1].y, acc0[2].x, acc0[2].y, acc0[3].x, acc0[3].y};
        float bb[8] = {b0.x, b0.y, b0.z, b0.w, b1.x, b1.y, b1.z, b1.w};
        float o[8];
        #pragma unroll
        for (int k = 0; k < 8; ++k) {
            float v = va[k] * dinv + bb[k];
            o[k] = v > 0.f ? v : (__expf(v) - 1.f);   // ELU
        }
        uint4 pk;
        pk.x = (unsigned)f2bf(o[0]) | ((unsigned)f2bf(o[1]) << 16);
        pk.y = (unsigned)f2bf(o[2]) | ((unsigned)f2bf(o[3]) << 16);
        pk.z = (unsigned)f2bf(o[4]) | ((unsigned)f2bf(o[5]) << 16);
        pk.w = (unsigned)f2bf(o[6]) | ((unsigned)f2bf(o[7]) << 16);
        *reinterpret_cast<uint4*>(&X2b[(size_t)node * 128 + c * 8]) = pk;
    }
}

// ---------------------------------------------------------------- aggregation layer2 (+bias) -> out
// 1 wave/node; stage 48 slots (key + inline exp), shfl-broadcast; 12 groups x 5 ch-lanes; 2 gathers in flight
__global__ __launch_bounds__(256) void aggregate2(const unsigned short* __restrict__ Hb,
                                                  const float* __restrict__ a_s, const float* __restrict__ a_d,
                                                  const int* __restrict__ offs, const unsigned int* __restrict__ keys,
                                                  const float* __restrict__ bias, float* __restrict__ out, int n) {
    int t = threadIdx.x, lane = t & 63, wid = t >> 6;
    int node = blockIdx.x * 4 + wid;
    if (node >= n) return;
    int g = lane / 5, c = lane - g * 5;
    bool dead = (g >= 12);
    if (dead) { g = 0; c = 0; }
    int beg = offs[node], deg = offs[node + 1] - beg;
    float adv = a_d[node];
    float den = 0.f;
    float2 acc0[4], acc1[4];
    #pragma unroll
    for (int m = 0; m < 4; ++m) { acc0[m] = make_float2(0.f, 0.f); acc1[m] = make_float2(0.f, 0.f); }

    for (int base = 0; base < deg; base += 48) {
        int nslots = min(48, deg - base);
        int s_l = 0; float w_l = 0.f;
        if (lane < nslots) {
            s_l = (int)(keys[beg + base + lane] & 0xFFFFu);
            w_l = __expf(lrelu(a_s[s_l] + adv));
        }
        den += w_l;
        for (int j = 0; j < nslots; j += 24) {
            int j0 = j + g, j1 = j + 12 + g;         // <= 47, staged zeros past deg
            int   sa = __shfl(s_l, j0); float wa = __shfl(w_l, j0);
            int   sb = __shfl(s_l, j1); float wb = __shfl(w_l, j1);
            uint4 ha = *reinterpret_cast<const uint4*>(&Hb[(size_t)sa * 40 + c * 8]);
            uint4 hb = *reinterpret_cast<const uint4*>(&Hb[(size_t)sb * 40 + c * 8]);
            fma8(acc0, wa, ha);
            fma8(acc1, wb, hb);
        }
    }
    #pragma unroll
    for (int m = 0; m < 4; ++m) { acc0[m].x += acc1[m].x; acc0[m].y += acc1[m].y; }
    // dead lanes duplicated group 0 with real weights — zero them before merge
    if (lane >= 60) {
        #pragma unroll
        for (int m = 0; m < 4; ++m) acc0[m] = make_float2(0.f, 0.f);
    }
    #pragma unroll
    for (int sh = 32; sh > 0; sh >>= 1) den += __shfl_xor(den, sh);
    #pragma unroll
    for (int m = 0; m < 4; ++m) {
        float ax = acc0[m].x, ay = acc0[m].y;
        ax += __shfl(ax, lane + 30); ay += __shfl(ay, lane + 30);
        ax += __shfl(ax, lane + 15); ay += __shfl(ay, lane + 15);
        float ax5 = __shfl(ax, lane + 5),  ay5 = __shfl(ay, lane + 5);
        float ax10 = __shfl(ax, lane + 10), ay10 = __shfl(ay, lane + 10);
        acc0[m].x = ax + ax5 + ax10;
        acc0[m].y = ay + ay5 + ay10;
    }
    if (lane < 5) {
        float dinv = 1.f / (den + 1e-16f);
        float4 b0 = *reinterpret_cast<const float4*>(&bias[c * 8]);
        float4 b1 = *reinterpret_cast<const float4*>(&bias[c * 8 + 4]);
        float4 o0, o1;
        o0.x = acc0[0].x * dinv + b0.x; o0.y = acc0[0].y * dinv + b0.y;
        o0.z = acc0[1].x * dinv + b0.z; o0.w = acc0[1].y * dinv + b0.w;
        o1.x = acc0[2].x * dinv + b1.x; o1.y = acc0[2].y * dinv + b1.y;
        o1.z = acc0[3].x * dinv + b1.z; o1.w = acc0[3].y * dinv + b1.w;
        *reinterpret_cast<float4*>(&out[(size_t)node * 40 + c * 8])     = o0;
        *reinterpret_cast<float4*>(&out[(size_t)node * 40 + c * 8 + 4]) = o1;
    }
}

// ---------------------------------------------------------------- launch
extern "C" void kernel_launch(void* const* d_in, const int* in_sizes, int n_in,
                              void* d_out, int out_size, void* d_ws, size_t ws_size,
                              hipStream_t stream) {
    (void)in_sizes; (void)n_in; (void)out_size; (void)ws_size;
    const float* x    = (const float*)d_in[0];
    const int*   ei   = (const int*)d_in[1];
    const float* W1   = (const float*)d_in[2];
    const float* as1w = (const float*)d_in[3];
    const float* ad1w = (const float*)d_in[4];
    const float* b1   = (const float*)d_in[5];
    const float* W2   = (const float*)d_in[6];
    const float* as2w = (const float*)d_in[7];
    const float* ad2w = (const float*)d_in[8];
    const float* b2   = (const float*)d_in[9];
    float* out = (float*)d_out;

    float* ws = (float*)d_ws;
    float* h1slot = ws; ws += (size_t)N_NODES * 128;
    float* x2slot = ws; ws += (size_t)N_NODES * 128;
    float* a_s1 = ws; ws += N_NODES * 2;
    float* a_d1 = ws; ws += N_NODES * 2;
    float* a_s2 = ws; ws += N_NODES;
    float* a_d2 = ws; ws += N_NODES;
    float* h2slot = ws; ws += (size_t)N_NODES * 40;
    int* offs  = (int*)ws;                               // 50432
    int* ghist = offs + 50432;                           // 65536
    int* gbase = ghist + 65536;                          // 65536
    int* bsum  = gbase + 65536;                          // 64
    int* total = bsum + 64;                              // 4
    unsigned int* tmpk = (unsigned int*)(total + 4);     // E_TOT
    unsigned int* keys = tmpk + E_TOT;                   // E_TOT
    uint4* ew = (uint4*)(keys + E_TOT);                  // E_TOT uint4
    unsigned short* Wt1 = (unsigned short*)(ew + E_TOT);
    unsigned short* Wt2 = Wt1 + 128 * 128;

    unsigned short* h1b = (unsigned short*)h1slot;
    unsigned short* x2b = (unsigned short*)x2slot;
    unsigned short* h2b = (unsigned short*)h2slot;

    hist_w<<<256, 256, 0, stream>>>(ei, ghist, W1, W2, Wt1, Wt2);
    scan_local<<<64, 256, 0, stream>>>(ghist, gbase, bsum, 65536);
    scan_addoff<<<64, 256, 0, stream>>>(gbase, bsum, total, 65536, 64);
    gemm1_scatter<<<G1_BLOCKS + 256, 256, 0, stream>>>(x, Wt1, as1w, ad1w, h1b, a_s1, a_d1, ei, gbase, tmpk);
    sort_w<<<196, 256, 0, stream>>>(tmpk, gbase, a_s1, a_d1, keys, ew, offs);
    aggregate1<<<(N_NODES + 3) / 4, 256, 0, stream>>>(h1b, ew, offs, b1, x2b, N_NODES);
    gemm2_mfma<<<(N_NODES + 63) / 64, 256, 0, stream>>>(x2b, Wt2, as2w, ad2w, h2b, a_s2, a_d2, N_NODES);
    aggregate2<<<(N_NODES + 3) / 4, 256, 0, stream>>>(h2b, a_s2, a_d2, offs, keys, b2, out, N_NODES);
}